// Round 2
// baseline (79.478 us; speedup 1.0000x reference)
//
#include <hip/hip_runtime.h>
#include <hip/hip_bf16.h>

// Problem: B=8, N=2048, K=32, C=256, COND=512 — ALL FLOAT32 I/O, coords int32.
//  0 node_feats [8,2048,256] f32
//  1 cond_feats [8,512] f32
//  2 W_cond     [512,512] f32
//  3 b_cond     [512] f32
//  4 W_film     [256,256] f32
//  5 b_film     [256] f32
//  6 weights    [8,65536,1] f32
//  7 params     [8,65536,1] f32
//  8 coords     [524288] int32 in [0,16384)
// Output: f32 [8,2048,256]

typedef unsigned short u16;
typedef unsigned int u32;

typedef __attribute__((ext_vector_type(8))) __bf16 bf16x8;
typedef __attribute__((ext_vector_type(4))) float f32x4;

__device__ __forceinline__ float b2f(u16 u) {
  union { u32 i; float f; } x; x.i = ((u32)u) << 16; return x.f;
}
__device__ __forceinline__ u16 f2b(float f) {
  union { float f; u32 i; } x; x.f = f;
  u32 r = (x.i + 0x7fffu + ((x.i >> 16) & 1u)) >> 16;
  return (u16)r;
}

// ---------------------------------------------------------------------------
// K0: repack W_film (f32 [256,256]) into bf16 B-fragment order for
//     mfma_f32_16x16x32_bf16:
//     Wp[((ct*8 + ks)*64 + lane)*8 + j] = bf16(W[(ks*32 + (lane>>4)*8 + j)*256 + ct*16 + (lane&15)])
// ---------------------------------------------------------------------------
__global__ __launch_bounds__(256) void k_repack(const float* __restrict__ W,
                                                u16* __restrict__ Wp) {
  int i = blockIdx.x * 256 + threadIdx.x;   // 65536 total
  int j  = i & 7;
  int l  = (i >> 3) & 63;
  int ks = (i >> 9) & 7;
  int ct = i >> 12;
  int k   = ks * 32 + ((l >> 4) << 3) + j;
  int col = ct * 16 + (l & 15);
  Wp[i] = f2b(W[k * 256 + col]);
}

// ---------------------------------------------------------------------------
// K1: gamma/beta = cond_feats @ W_cond + b_cond  (gamma += 1), all f32
//     gb[b][0:256] = gamma, gb[b][256:512] = beta
// ---------------------------------------------------------------------------
__global__ __launch_bounds__(512) void k_cond(const float* __restrict__ cond,
                                              const float* __restrict__ Wc,
                                              const float* __restrict__ bc,
                                              float* __restrict__ gb) {
  int b = blockIdx.x;        // 8
  int j = threadIdx.x;       // 512
  __shared__ float cf[512];
  cf[j] = cond[b * 512 + j];
  __syncthreads();
  float acc = bc[j];
  #pragma unroll 8
  for (int i = 0; i < 512; ++i)
    acc += cf[i] * Wc[i * 512 + j];
  if (j < 256) acc += 1.0f;
  gb[b * 512 + j] = acc;
}

// ---------------------------------------------------------------------------
// K2: nnf = bf16( relu(LN(node_feats @ W_film + b_film) * gamma + beta) )
// One wave per 16 rows; 16 col-tiles of mfma_f32_16x16x32_bf16 over K=256.
// A fragment: lane l -> row (l&15), k = ks*32 + (l>>4)*8 + j
// D fragment: col = ct*16 + (l&15), row = row0 + (l>>4)*4 + r   [m89-verified]
// ---------------------------------------------------------------------------
__global__ __launch_bounds__(64) void k_film(const float* __restrict__ A,
                                             const u16* __restrict__ Wp,
                                             const float* __restrict__ bfm,
                                             const float* __restrict__ gb,
                                             u16* __restrict__ nnf) {
  const int l = threadIdx.x;          // 0..63
  const int row0 = blockIdx.x * 16;   // 1024 blocks -> 16384 rows
  const int b = row0 >> 11;           // batch (2048 rows/batch; tiles don't straddle)

  f32x4 acc[16];
  #pragma unroll
  for (int ct = 0; ct < 16; ++ct) {
    acc[ct].x = 0.f; acc[ct].y = 0.f; acc[ct].z = 0.f; acc[ct].w = 0.f;
  }

  const float* arow = A + (size_t)(row0 + (l & 15)) * 256 + ((l >> 4) << 3);
  const u16* wl = Wp + l * 8;

  for (int ks = 0; ks < 8; ++ks) {
    float4 a0 = *(const float4*)(arow + ks * 32);
    float4 a1 = *(const float4*)(arow + ks * 32 + 4);
    bf16x8 af;
    af[0] = (__bf16)a0.x; af[1] = (__bf16)a0.y;
    af[2] = (__bf16)a0.z; af[3] = (__bf16)a0.w;
    af[4] = (__bf16)a1.x; af[5] = (__bf16)a1.y;
    af[6] = (__bf16)a1.z; af[7] = (__bf16)a1.w;
    const u16* wp = wl + ks * 512;
    #pragma unroll
    for (int ct = 0; ct < 16; ++ct) {
      bf16x8 bfr = *(const bf16x8*)(wp + ct * 4096);
      acc[ct] = __builtin_amdgcn_mfma_f32_16x16x32_bf16(af, bfr, acc[ct], 0, 0, 0);
    }
  }

  // bias + row sums / sumsq
  float s[4] = {0.f, 0.f, 0.f, 0.f};
  float q[4] = {0.f, 0.f, 0.f, 0.f};
  #pragma unroll
  for (int ct = 0; ct < 16; ++ct) {
    float bcol = bfm[ct * 16 + (l & 15)];
    #pragma unroll
    for (int r = 0; r < 4; ++r) {
      float v = acc[ct][r] + bcol;
      acc[ct][r] = v;
      s[r] += v;
      q[r] += v * v;
    }
  }
  // reduce across the 16 lanes sharing the same 4 rows
  #pragma unroll
  for (int m = 1; m < 16; m <<= 1) {
    #pragma unroll
    for (int r = 0; r < 4; ++r) {
      s[r] += __shfl_xor(s[r], m);
      q[r] += __shfl_xor(q[r], m);
    }
  }
  float mu[4], rs[4];
  #pragma unroll
  for (int r = 0; r < 4; ++r) {
    mu[r] = s[r] * (1.0f / 256.0f);
    float var = q[r] * (1.0f / 256.0f) - mu[r] * mu[r];
    rs[r] = rsqrtf(var + 1e-5f);
  }

  const int colb = l & 15;
  const int rowb = row0 + ((l >> 4) << 2);
  #pragma unroll
  for (int ct = 0; ct < 16; ++ct) {
    int col = ct * 16 + colb;
    float g  = gb[b * 512 + col];
    float be = gb[b * 512 + 256 + col];
    #pragma unroll
    for (int r = 0; r < 4; ++r) {
      float h = (acc[ct][r] - mu[r]) * rs[r];
      float o = fmaxf(h * g + be, 0.f);
      nnf[(size_t)(rowb + r) * 256 + col] = f2b(o);
    }
  }
}

// ---------------------------------------------------------------------------
// K3: out = relu(nnf + sum_k ew[k] * nnf[coords[k]])   (f32 out, bf16 table)
// One wave per (b,n) row; lane owns 4 consecutive cols.
// ---------------------------------------------------------------------------
__global__ __launch_bounds__(256) void k_gather(const u16* __restrict__ nnf,
                                                const float* __restrict__ wts,
                                                const float* __restrict__ prm,
                                                const int* __restrict__ coords,
                                                float* __restrict__ out) {
  int t = blockIdx.x * 256 + threadIdx.x;
  int row  = t >> 6;        // 0..16383
  int lane = t & 63;
  int base = row * 32;
  int col  = lane * 4;

  float a0 = 0.f, a1 = 0.f, a2 = 0.f, a3 = 0.f;
  #pragma unroll 8
  for (int k = 0; k < 32; ++k) {
    int idx  = coords[base + k];
    float ew = wts[base + k] * prm[base + k];
    ushort4 v = *(const ushort4*)(nnf + (size_t)idx * 256 + col);
    a0 += ew * b2f(v.x);
    a1 += ew * b2f(v.y);
    a2 += ew * b2f(v.z);
    a3 += ew * b2f(v.w);
  }
  ushort4 sv = *(const ushort4*)(nnf + (size_t)row * 256 + col);
  float4 o;
  o.x = fmaxf(b2f(sv.x) + a0, 0.f);
  o.y = fmaxf(b2f(sv.y) + a1, 0.f);
  o.z = fmaxf(b2f(sv.z) + a2, 0.f);
  o.w = fmaxf(b2f(sv.w) + a3, 0.f);
  *(float4*)(out + (size_t)row * 256 + col) = o;
}

// ---------------------------------------------------------------------------
extern "C" void kernel_launch(void* const* d_in, const int* in_sizes, int n_in,
                              void* d_out, int out_size, void* d_ws, size_t ws_size,
                              hipStream_t stream) {
  const float* node = (const float*)d_in[0];
  const float* cond = (const float*)d_in[1];
  const float* Wc   = (const float*)d_in[2];
  const float* bc   = (const float*)d_in[3];
  const float* Wf   = (const float*)d_in[4];
  const float* bf   = (const float*)d_in[5];
  const float* wts  = (const float*)d_in[6];
  const float* prm  = (const float*)d_in[7];
  const int* coords = (const int*)d_in[8];
  float* out = (float*)d_out;

  char* ws = (char*)d_ws;
  float* gb = (float*)ws;                       // 8*512 f32      = 16 KB
  u16* Wp   = (u16*)(ws + 16384);               // 65536 u16      = 128 KB
  u16* nnf  = (u16*)(ws + 16384 + 131072);      // 16384*256 bf16 = 8 MB

  k_repack<<<dim3(256), dim3(256), 0, stream>>>(Wf, Wp);
  k_cond<<<dim3(8), dim3(512), 0, stream>>>(cond, Wc, bc, gb);
  k_film<<<dim3(1024), dim3(64), 0, stream>>>(node, Wp, bf, gb, nnf);
  k_gather<<<dim3(4096), dim3(256), 0, stream>>>(nnf, wts, prm, coords, out);
}

// Round 3
// 70.691 us; speedup vs baseline: 1.1243x; 1.1243x over previous
//
#include <hip/hip_runtime.h>

// Problem: B=8, N=2048, K=32, C=256, COND=512 — ALL FLOAT32 I/O, coords int32.
//  0 node_feats [8,2048,256] f32
//  1 cond_feats [8,512] f32
//  2 W_cond     [512,512] f32
//  3 b_cond     [512] f32
//  4 W_film     [256,256] f32
//  5 b_film     [256] f32
//  6 weights    [8,65536,1] f32
//  7 params     [8,65536,1] f32
//  8 coords     [524288] int32 in [0,16384)
// Output: f32 [8,2048,256]

typedef unsigned short u16;
typedef unsigned int u32;

typedef __attribute__((ext_vector_type(8))) __bf16 bf16x8;
typedef __attribute__((ext_vector_type(4))) float f32x4;

__device__ __forceinline__ float b2f(u16 u) {
  union { u32 i; float f; } x; x.i = ((u32)u) << 16; return x.f;
}
__device__ __forceinline__ u16 f2b(float f) {
  union { float f; u32 i; } x; x.f = f;
  u32 r = (x.i + 0x7fffu + ((x.i >> 16) & 1u)) >> 16;
  return (u16)r;
}

// ---------------------------------------------------------------------------
// K0: prep = W_film repack to MFMA-B fragment order (blocks 0..31)
//           + cond GEMM gamma/beta (blocks 32..39)
// Wp[((ct*8+ks)*64+l)*8+j] = bf16(Wf[(ks*32+(l>>4)*8+j)*256 + ct*16+(l&15)])
// gb[b][0:256]=gamma(+1), gb[b][256:512]=beta
// ---------------------------------------------------------------------------
__global__ __launch_bounds__(256) void k_prep(const float* __restrict__ Wf,
                                              u16* __restrict__ Wp,
                                              const float* __restrict__ cond,
                                              const float* __restrict__ Wc,
                                              const float* __restrict__ bc,
                                              float* __restrict__ gb) {
  if (blockIdx.x < 32) {
    int i0 = blockIdx.x * 2048 + threadIdx.x;
    #pragma unroll
    for (int u = 0; u < 8; ++u) {
      int i = i0 + u * 256;
      int j  = i & 7;
      int l  = (i >> 3) & 63;
      int ks = (i >> 9) & 7;
      int ct = i >> 12;
      int k   = ks * 32 + ((l >> 4) << 3) + j;
      int col = ct * 16 + (l & 15);
      Wp[i] = f2b(Wf[k * 256 + col]);
    }
  } else {
    int b = blockIdx.x - 32;
    int j = threadIdx.x;            // 0..255
    __shared__ float cf[512];
    cf[j]       = cond[b * 512 + j];
    cf[j + 256] = cond[b * 512 + 256 + j];
    __syncthreads();
    float a0 = bc[j], a1 = bc[j + 256];
    #pragma unroll 8
    for (int i = 0; i < 512; ++i) {
      float c = cf[i];
      a0 += c * Wc[i * 512 + j];
      a1 += c * Wc[i * 512 + 256 + j];
    }
    gb[b * 512 + j]       = a0 + 1.0f;   // gamma
    gb[b * 512 + 256 + j] = a1;          // beta
  }
}

// ---------------------------------------------------------------------------
// K2: nnf = bf16( relu(LN(node_feats @ W_film + b_film) * gamma + beta) )
// Block = 256 thr = 4 waves, 16 rows. A staged to LDS (bf16, stride 264).
// Wave w computes col-tiles ct = w*4..w*4+3 (64 cols), K=256 -> 32 MFMA/wave.
// LN stats: intra-wave shfl over 16-lane groups, cross-wave via LDS.
// D frag: col = ct*16+(l&15), row = row0 + (l>>4)*4 + r   [m89-verified]
// ---------------------------------------------------------------------------
__global__ __launch_bounds__(256) void k_film(const float* __restrict__ A,
                                              const u16* __restrict__ Wp,
                                              const float* __restrict__ bfm,
                                              const float* __restrict__ gb,
                                              u16* __restrict__ nnf) {
  const int tid = threadIdx.x;
  const int l = tid & 63;
  const int w = tid >> 6;             // wave 0..3
  const int row0 = blockIdx.x * 16;   // 1024 blocks
  const int b = row0 >> 11;

  __shared__ u16 As[16 * 264];        // padded: 528B row stride (33*16B)
  __shared__ float red[4][4][2][4];   // [wave][group][s|q][r]

  // Stage A tile: thread t -> row t>>4, cols (t&15)*16 .. +15
  {
    int r = tid >> 4, c0 = (tid & 15) * 16;
    const float* src = A + (size_t)(row0 + r) * 256 + c0;
    u16* dst = As + r * 264 + c0;
    #pragma unroll
    for (int u = 0; u < 16; u += 4) {
      float4 v = *(const float4*)(src + u);
      dst[u + 0] = f2b(v.x); dst[u + 1] = f2b(v.y);
      dst[u + 2] = f2b(v.z); dst[u + 3] = f2b(v.w);
    }
  }
  __syncthreads();

  f32x4 acc[4];
  #pragma unroll
  for (int c = 0; c < 4; ++c) {
    acc[c].x = 0.f; acc[c].y = 0.f; acc[c].z = 0.f; acc[c].w = 0.f;
  }

  // A frag: lane l -> row (l&15), k = ks*32 + (l>>4)*8 + j (16B contiguous)
  const u16* asrc = As + (l & 15) * 264 + ((l >> 4) << 3);
  const u16* wl = Wp + (size_t)l * 8;

  #pragma unroll
  for (int ks = 0; ks < 8; ++ks) {
    bf16x8 af = *(const bf16x8*)(asrc + ks * 32);
    #pragma unroll
    for (int c = 0; c < 4; ++c) {
      int ct = w * 4 + c;
      bf16x8 bfr = *(const bf16x8*)(wl + ((size_t)(ct * 8 + ks)) * 512);
      acc[c] = __builtin_amdgcn_mfma_f32_16x16x32_bf16(af, bfr, acc[c], 0, 0, 0);
    }
  }

  // bias + partial row sums/sumsq over this wave's 64 cols
  float s[4] = {0.f, 0.f, 0.f, 0.f};
  float q[4] = {0.f, 0.f, 0.f, 0.f};
  #pragma unroll
  for (int c = 0; c < 4; ++c) {
    float bcol = bfm[(w * 4 + c) * 16 + (l & 15)];
    #pragma unroll
    for (int r = 0; r < 4; ++r) {
      float v = acc[c][r] + bcol;
      acc[c][r] = v;
      s[r] += v;
      q[r] += v * v;
    }
  }
  #pragma unroll
  for (int m = 1; m < 16; m <<= 1) {
    #pragma unroll
    for (int r = 0; r < 4; ++r) {
      s[r] += __shfl_xor(s[r], m);
      q[r] += __shfl_xor(q[r], m);
    }
  }
  const int g = l >> 4;               // lane group = row block
  if ((l & 15) == 0) {
    #pragma unroll
    for (int r = 0; r < 4; ++r) {
      red[w][g][0][r] = s[r];
      red[w][g][1][r] = q[r];
    }
  }
  __syncthreads();

  float mu[4], rs[4];
  #pragma unroll
  for (int r = 0; r < 4; ++r) {
    float ss = red[0][g][0][r] + red[1][g][0][r] + red[2][g][0][r] + red[3][g][0][r];
    float qq = red[0][g][1][r] + red[1][g][1][r] + red[2][g][1][r] + red[3][g][1][r];
    mu[r] = ss * (1.0f / 256.0f);
    float var = qq * (1.0f / 256.0f) - mu[r] * mu[r];
    rs[r] = rsqrtf(var + 1e-5f);
  }

  const int rowb = row0 + (g << 2);
  #pragma unroll
  for (int c = 0; c < 4; ++c) {
    int col = (w * 4 + c) * 16 + (l & 15);
    float ga = gb[b * 512 + col];
    float be = gb[b * 512 + 256 + col];
    #pragma unroll
    for (int r = 0; r < 4; ++r) {
      float h = (acc[c][r] - mu[r]) * rs[r];
      nnf[(size_t)(rowb + r) * 256 + col] = f2b(fmaxf(h * ga + be, 0.f));
    }
  }
}

// ---------------------------------------------------------------------------
// K3: out = relu(nnf + sum_k ew[k]*nnf[coords[k]])  (f32 out, bf16 table)
// One wave per row. Lane-parallel coord/ew load + shfl broadcast; all 32
// row-gathers issued up-front into a register array (full unroll -> no scratch).
// ---------------------------------------------------------------------------
__global__ __launch_bounds__(256) void k_gather(const u16* __restrict__ nnf,
                                                const float* __restrict__ wts,
                                                const float* __restrict__ prm,
                                                const int* __restrict__ coords,
                                                float* __restrict__ out) {
  int t = blockIdx.x * 256 + threadIdx.x;
  int row  = t >> 6;          // 0..16383
  int lane = t & 63;

  int base = row * 32 + (lane & 31);
  int idx_l  = coords[base];
  float ew_l = wts[base] * prm[base];

  const u16* colp = nnf + lane * 4;

  ushort4 v[32];
  #pragma unroll
  for (int k = 0; k < 32; ++k) {
    int idx = __shfl(idx_l, k);
    v[k] = *(const ushort4*)(colp + ((size_t)idx << 8));
  }

  float a0 = 0.f, a1 = 0.f, a2 = 0.f, a3 = 0.f;
  #pragma unroll
  for (int k = 0; k < 32; ++k) {
    float ew = __shfl(ew_l, k);
    a0 += ew * b2f(v[k].x);
    a1 += ew * b2f(v[k].y);
    a2 += ew * b2f(v[k].z);
    a3 += ew * b2f(v[k].w);
  }

  ushort4 sv = *(const ushort4*)(colp + ((size_t)row << 8));
  float4 o;
  o.x = fmaxf(b2f(sv.x) + a0, 0.f);
  o.y = fmaxf(b2f(sv.y) + a1, 0.f);
  o.z = fmaxf(b2f(sv.z) + a2, 0.f);
  o.w = fmaxf(b2f(sv.w) + a3, 0.f);
  *(float4*)(out + (size_t)row * 256 + lane * 4) = o;
}

// ---------------------------------------------------------------------------
extern "C" void kernel_launch(void* const* d_in, const int* in_sizes, int n_in,
                              void* d_out, int out_size, void* d_ws, size_t ws_size,
                              hipStream_t stream) {
  const float* node = (const float*)d_in[0];
  const float* cond = (const float*)d_in[1];
  const float* Wc   = (const float*)d_in[2];
  const float* bc   = (const float*)d_in[3];
  const float* Wf   = (const float*)d_in[4];
  const float* bf   = (const float*)d_in[5];
  const float* wts  = (const float*)d_in[6];
  const float* prm  = (const float*)d_in[7];
  const int* coords = (const int*)d_in[8];
  float* out = (float*)d_out;

  char* ws = (char*)d_ws;
  float* gb = (float*)ws;                       // 8*512 f32      = 16 KB
  u16* Wp   = (u16*)(ws + 16384);               // 65536 u16      = 128 KB
  u16* nnf  = (u16*)(ws + 16384 + 131072);      // 16384*256 bf16 = 8 MB

  k_prep<<<dim3(40), dim3(256), 0, stream>>>(Wf, Wp, cond, Wc, bc, gb);
  k_film<<<dim3(1024), dim3(256), 0, stream>>>(node, Wp, bf, gb, nnf);
  k_gather<<<dim3(4096), dim3(256), 0, stream>>>(nnf, wts, prm, coords, out);
}